// Round 4
// baseline (222.229 us; speedup 1.0000x reference)
//
#include <hip/hip_runtime.h>
#include <hip/hip_cooperative_groups.h>
#include <math.h>

namespace cg = cooperative_groups;

#define MARGIN 0.3f
#define GRID_BLOCKS 512
#define BLOCK 256

// Single fused cooperative kernel. ws layout (Npad = ceil(n/256)*256):
//   a[Npad]       float   chunk-compacted sigmoid of positives (+1e30 sentinel tail per chunk)
//   b[Npad]       float   chunk-compacted margin+sigmoid of negatives (-1e30 sentinel tail)
//   pc[numChunks] uint    positives per chunk
//   nc[numChunks] uint    negatives per chunk
//   partials[GRID_BLOCKS] double
// All ws slots written unconditionally before being read — no zeroing needed.

__global__ __launch_bounds__(BLOCK) void fused_triplet_kernel(
        const float* __restrict__ inputs,
        const int* __restrict__ targets,
        float* __restrict__ a,
        float* __restrict__ b,
        unsigned int* __restrict__ pc,
        unsigned int* __restrict__ nc,
        double* __restrict__ partials,
        float* __restrict__ out,
        int n) {
    cg::grid_group grid = cg::this_grid();
    const int tid = threadIdx.x;
    const int lane = tid & 63, wave = tid >> 6;
    const int numChunks = (n + 255) / 256;
    const int Npad = numChunks * 256;

    __shared__ unsigned int wP[4], wN[4];
    __shared__ float4 bs4[64];
    float* bs = (float*)bs4;
    __shared__ double wsum[4];
    __shared__ unsigned int fp[4], fq[4];

    // ---- Phase 1: per-chunk local compaction (no cross-block comms) ----
    for (int c = blockIdx.x; c < numChunks; c += gridDim.x) {
        const int base = c * 256;
        const int i = base + tid;
        const bool valid = (i < n);
        float x = valid ? inputs[i] : 0.0f;
        int   t = valid ? targets[i] : -1;
        float s = 1.0f / (1.0f + expf(-x));
        bool isPos = valid && (t == 1);
        bool isNeg = valid && (t == 0);

        // blanket sentinel fill, then compact-write after barrier
        a[base + tid] = 1e30f;
        b[base + tid] = -1e30f;

        unsigned long long mP = __ballot(isPos);
        unsigned long long mN = __ballot(isNeg);
        unsigned long long below = (1ull << lane) - 1ull;
        unsigned int pPre = (unsigned int)__popcll(mP & below);
        unsigned int nPre = (unsigned int)__popcll(mN & below);
        if (lane == 0) { wP[wave] = (unsigned int)__popcll(mP);
                         wN[wave] = (unsigned int)__popcll(mN); }
        __syncthreads();  // orders sentinel fill before compact writes, publishes wP/wN
        unsigned int offP = 0, offN = 0;
        for (int w = 0; w < wave; w++) { offP += wP[w]; offN += wN[w]; }
        if (isPos) a[base + offP + pPre] = s;
        if (isNeg) b[base + offN + nPre] = MARGIN + s;
        if (tid == 0) {
            pc[c] = wP[0] + wP[1] + wP[2] + wP[3];
            nc[c] = wN[0] + wN[1] + wN[2] + wN[3];
        }
        __syncthreads();  // protect wP/wN for next chunk iteration
    }
    __threadfence();
    grid.sync();

    // ---- Phase 2: tiled pair sum over chunk-compacted arrays ----
    const int tilesI = (Npad + 511) / 512;
    const int tilesJ = numChunks;          // 256 cols = one chunk per tile
    const int numTiles = tilesI * tilesJ;
    double dlocal = 0.0;

    for (int tile = blockIdx.x; tile < numTiles; tile += gridDim.x) {
        int ti = tile / tilesJ;
        int tj = tile - ti * tilesJ;

        __syncthreads();                   // protect bs from previous tile
        bs[tid] = b[tj * 256 + tid];
        __syncthreads();

        unsigned int ncv = nc[tj];
        int i0 = ti * 512 + tid;
        float a0 = (i0        < Npad) ? a[i0]       : 1e30f;
        float a1 = (i0 + 256  < Npad) ? a[i0 + 256] : 1e30f;

        bool rowLive = (a0 < 1e29f) || (a1 < 1e29f);
        if (__any(rowLive)) {              // whole-wave skip of sentinel rows
            int nq4 = (int)((ncv + 3u) >> 2);   // sentinel padding covers remainder
            float c0 = 0.0f, c1 = 0.0f;
            #pragma unroll 4
            for (int q4 = 0; q4 < nq4; q4++) {
                float4 b4 = bs4[q4];
                c0 += fmaxf(b4.x - a0, 0.0f);
                c0 += fmaxf(b4.y - a0, 0.0f);
                c0 += fmaxf(b4.z - a0, 0.0f);
                c0 += fmaxf(b4.w - a0, 0.0f);
                c1 += fmaxf(b4.x - a1, 0.0f);
                c1 += fmaxf(b4.y - a1, 0.0f);
                c1 += fmaxf(b4.z - a1, 0.0f);
                c1 += fmaxf(b4.w - a1, 0.0f);
            }
            dlocal += (double)c0 + (double)c1;
        }
    }

    // block reduction -> partials[blockIdx]
    for (int off = 32; off > 0; off >>= 1)
        dlocal += __shfl_down(dlocal, off, 64);
    if (lane == 0) wsum[wave] = dlocal;
    __syncthreads();
    if (tid == 0)
        partials[blockIdx.x] = wsum[0] + wsum[1] + wsum[2] + wsum[3];
    __threadfence();
    grid.sync();

    // ---- Phase 3: block 0 finalizes ----
    if (blockIdx.x == 0) {
        double tsum = 0.0;
        unsigned int p = 0, q = 0;
        for (int k = tid; k < (int)gridDim.x; k += 256) tsum += partials[k];
        for (int k = tid; k < numChunks; k += 256) { p += pc[k]; q += nc[k]; }
        for (int off = 32; off > 0; off >>= 1) {
            tsum += __shfl_down(tsum, off, 64);
            p    += __shfl_down(p, off, 64);
            q    += __shfl_down(q, off, 64);
        }
        if (lane == 0) { wsum[wave] = tsum; fp[wave] = p; fq[wave] = q; }
        __syncthreads();
        if (tid == 0) {
            double T = wsum[0] + wsum[1] + wsum[2] + wsum[3];
            double P = (double)(fp[0] + fp[1] + fp[2] + fp[3]);
            double Q = (double)(fq[0] + fq[1] + fq[2] + fq[3]);
            out[0] = (P > 0.0 && Q > 0.0) ? (float)(T / (P * Q)) : 0.0f;
        }
    }
}

extern "C" void kernel_launch(void* const* d_in, const int* in_sizes, int n_in,
                              void* d_out, int out_size, void* d_ws, size_t ws_size,
                              hipStream_t stream) {
    const float* inputs  = (const float*)d_in[0];
    const int*   targets = (const int*)d_in[1];
    float* out = (float*)d_out;
    int n = in_sizes[0];

    int numChunks = (n + 255) / 256;
    int Npad = numChunks * 256;

    char* ws = (char*)d_ws;
    float*        a        = (float*)ws;
    float*        b        = a + Npad;
    unsigned int* pc       = (unsigned int*)(b + Npad);
    unsigned int* nc       = pc + numChunks;
    double*       partials = (double*)(ws + (size_t)8 * Npad + (size_t)8 * numChunks);

    void* args[] = { (void*)&inputs, (void*)&targets, (void*)&a, (void*)&b,
                     (void*)&pc, (void*)&nc, (void*)&partials, (void*)&out, (void*)&n };
    hipLaunchCooperativeKernel((const void*)fused_triplet_kernel,
                               dim3(GRID_BLOCKS), dim3(BLOCK), args, 0, stream);
}

// Round 5
// 80.142 us; speedup vs baseline: 2.7729x; 2.7729x over previous
//
#include <hip/hip_runtime.h>
#include <math.h>

#define MARGIN 0.3f
#define PAIR_BLOCKS 512

// Workspace layout (Npad = ceil(n/256)*256, numChunks = Npad/256):
//   [0]            double total        (zeroed by prep block 0)
//   [8]            uint   done         (zeroed by prep block 0)
//   [16]           float  a[Npad]      chunk-compacted sigmoid of positives, +1e30 sentinel tail
//   [16+4*Npad]    float  b[Npad]      chunk-compacted margin+sigmoid of negatives, -1e30 tail
//   [16+8*Npad]    uint   pc[numChunks]
//   [...]          uint   nc[numChunks]
// Every slot is written before it is read; no memset dispatch needed.

__global__ __launch_bounds__(256) void prep_compact_kernel(
        const float* __restrict__ inputs,
        const int* __restrict__ targets,
        float* __restrict__ a,
        float* __restrict__ b,
        unsigned int* __restrict__ pc,
        unsigned int* __restrict__ nc,
        double* __restrict__ total,
        unsigned int* __restrict__ done,
        int n) {
    __shared__ unsigned int wP[4], wN[4];
    const int tid = threadIdx.x;
    const int lane = tid & 63, wave = tid >> 6;
    const int base = blockIdx.x * 256;
    const int i = base + tid;
    const bool valid = (i < n);

    if (blockIdx.x == 0 && tid == 0) { *total = 0.0; *done = 0u; }

    float x = valid ? inputs[i] : 0.0f;
    int   t = valid ? targets[i] : -1;
    float s = 1.0f / (1.0f + expf(-x));
    bool isPos = valid && (t == 1);
    bool isNeg = valid && (t == 0);

    // blanket sentinel fill; compact overwrite after the barrier
    a[base + tid] = 1e30f;
    b[base + tid] = -1e30f;

    unsigned long long mP = __ballot(isPos);
    unsigned long long mN = __ballot(isNeg);
    unsigned long long below = (1ull << lane) - 1ull;
    unsigned int pPre = (unsigned int)__popcll(mP & below);
    unsigned int nPre = (unsigned int)__popcll(mN & below);
    if (lane == 0) { wP[wave] = (unsigned int)__popcll(mP);
                     wN[wave] = (unsigned int)__popcll(mN); }
    __syncthreads();   // orders sentinel fill before compact writes; publishes wP/wN
    unsigned int offP = 0, offN = 0;
    for (int w = 0; w < wave; w++) { offP += wP[w]; offN += wN[w]; }
    if (isPos) a[base + offP + pPre] = s;
    if (isNeg) b[base + offN + nPre] = MARGIN + s;
    if (tid == 0) {
        pc[blockIdx.x] = wP[0] + wP[1] + wP[2] + wP[3];
        nc[blockIdx.x] = wN[0] + wN[1] + wN[2] + wN[3];
    }
}

// Pair sum over chunk-compacted arrays: sum relu(b_j - a_i).
// 512-row x 256-col tiles; j-trip from nc[tj]; __any-skip of sentinel rows.
__global__ __launch_bounds__(256) void pair_reduce_kernel(
        const float* __restrict__ a,
        const float* __restrict__ b,
        const unsigned int* __restrict__ pc,
        const unsigned int* __restrict__ nc,
        double* __restrict__ total,
        unsigned int* __restrict__ done,
        float* __restrict__ out,
        int numChunks) {
    const int tid = threadIdx.x;
    const int lane = tid & 63, wave = tid >> 6;
    const int Npad = numChunks * 256;
    const int tilesI = (Npad + 511) / 512;
    const int tilesJ = numChunks;
    const int numTiles = tilesI * tilesJ;

    __shared__ float4 bs4[64];
    float* bs = (float*)bs4;
    __shared__ double wsum[4];
    __shared__ bool amLast;

    double dlocal = 0.0;

    for (int tile = blockIdx.x; tile < numTiles; tile += gridDim.x) {
        int ti = tile / tilesJ;
        int tj = tile - ti * tilesJ;

        __syncthreads();                       // protect bs from previous tile
        bs[tid] = b[tj * 256 + tid];
        unsigned int ncv = nc[tj];
        int i0 = ti * 512 + tid;
        float a0 = (i0       < Npad) ? a[i0]       : 1e30f;
        float a1 = (i0 + 256 < Npad) ? a[i0 + 256] : 1e30f;
        __syncthreads();

        bool rowLive = (a0 < 1e29f) || (a1 < 1e29f);
        if (__any(rowLive) && ncv > 0u) {
            int nq4 = (int)((ncv + 3u) >> 2);  // sentinel padding covers remainder
            float c0 = 0.0f, c1 = 0.0f;
            #pragma unroll 4
            for (int q4 = 0; q4 < nq4; q4++) {
                float4 b4 = bs4[q4];
                c0 += fmaxf(b4.x - a0, 0.0f);
                c0 += fmaxf(b4.y - a0, 0.0f);
                c0 += fmaxf(b4.z - a0, 0.0f);
                c0 += fmaxf(b4.w - a0, 0.0f);
                c1 += fmaxf(b4.x - a1, 0.0f);
                c1 += fmaxf(b4.y - a1, 0.0f);
                c1 += fmaxf(b4.z - a1, 0.0f);
                c1 += fmaxf(b4.w - a1, 0.0f);
            }
            dlocal += (double)c0 + (double)c1;
        }
    }

    // block reduction in double
    for (int off = 32; off > 0; off >>= 1)
        dlocal += __shfl_down(dlocal, off, 64);
    if (lane == 0) wsum[wave] = dlocal;
    __syncthreads();
    if (tid == 0) {
        double bsum = wsum[0] + wsum[1] + wsum[2] + wsum[3];
        atomicAdd(total, bsum);
        __threadfence();
        unsigned int prev = atomicAdd(done, 1u);
        amLast = (prev == gridDim.x - 1);
    }
    __syncthreads();

    if (amLast) {
        __threadfence();
        // parallel P/Q reduce over numChunks entries (one wave handles <=64 each pass)
        unsigned int p = 0, q = 0;
        for (int k = tid; k < numChunks; k += 256) { p += pc[k]; q += nc[k]; }
        for (int off = 32; off > 0; off >>= 1) {
            p += __shfl_down(p, off, 64);
            q += __shfl_down(q, off, 64);
        }
        __shared__ unsigned int fp[4], fq[4];
        if (lane == 0) { fp[wave] = p; fq[wave] = q; }
        __syncthreads();
        if (tid == 0) {
            double T = atomicAdd(total, 0.0);  // coherent read of final sum
            double P = (double)(fp[0] + fp[1] + fp[2] + fp[3]);
            double Q = (double)(fq[0] + fq[1] + fq[2] + fq[3]);
            out[0] = (P > 0.0 && Q > 0.0) ? (float)(T / (P * Q)) : 0.0f;
        }
    }
}

extern "C" void kernel_launch(void* const* d_in, const int* in_sizes, int n_in,
                              void* d_out, int out_size, void* d_ws, size_t ws_size,
                              hipStream_t stream) {
    const float* inputs  = (const float*)d_in[0];
    const int*   targets = (const int*)d_in[1];
    float* out = (float*)d_out;
    int n = in_sizes[0];

    int numChunks = (n + 255) / 256;
    int Npad = numChunks * 256;

    char* ws = (char*)d_ws;
    double*       total = (double*)(ws + 0);
    unsigned int* done  = (unsigned int*)(ws + 8);
    float*        a     = (float*)(ws + 16);
    float*        b     = a + Npad;
    unsigned int* pc    = (unsigned int*)(b + Npad);
    unsigned int* nc    = pc + numChunks;

    prep_compact_kernel<<<numChunks, 256, 0, stream>>>(
        inputs, targets, a, b, pc, nc, total, done, n);

    pair_reduce_kernel<<<PAIR_BLOCKS, 256, 0, stream>>>(
        a, b, pc, nc, total, done, out, numChunks);
}